// Round 1
// baseline (133.885 us; speedup 1.0000x reference)
//
#include <hip/hip_runtime.h>
#include <stdint.h>

typedef __bf16 bf16;
typedef bf16 bf16x8 __attribute__((ext_vector_type(8)));
typedef float f32x4 __attribute__((ext_vector_type(4)));
typedef uint32_t u32;
typedef uint16_t u16;
typedef u32 u32x2 __attribute__((ext_vector_type(2)));

#define BATCH 4
#define NSEQ  4096
#define DHEAD 128
#define QW    16          // q rows per wave
#define WAVES 4
#define QB    (QW*WAVES)  // 64 q rows per block
#define KB    32          // kv rows per iteration
#define LOG2E 1.44269504088896340736f

__device__ __forceinline__ u16 f2bf(float f) {
    u32 u = __builtin_bit_cast(u32, f);
    u += 0x7fff + ((u >> 16) & 1);   // RNE; inputs are finite normals
    return (u16)(u >> 16);
}

// ---------------- prep: fp32 x -> bf16 Xb (row-major) + XbT (transposed) ----------------
__global__ __launch_bounds__(256) void prep_kernel(const float* __restrict__ x,
                                                   u16* __restrict__ Xb,
                                                   u16* __restrict__ XbT) {
    __shared__ u16 tile[64][65];
    int bid = blockIdx.x;            // 512 blocks: b(4) x ntile(64) x dtile(2)
    int b  = bid >> 7;
    int nt = (bid >> 1) & 63;
    int dt = bid & 1;
    int n0 = nt * 64, d0 = dt * 64;
    int t = threadIdx.x;
    const float* xb = x + (size_t)b * NSEQ * DHEAD;
    u16* Xbb  = Xb  + (size_t)b * NSEQ * DHEAD;
    u16* XbTb = XbT + (size_t)b * DHEAD * NSEQ;
    #pragma unroll
    for (int i = 0; i < 16; i++) {
        int idx = t + i * 256;
        int r = idx >> 6, c = idx & 63;
        float f = xb[(size_t)(n0 + r) * DHEAD + d0 + c];
        u16 v = f2bf(f);
        Xbb[(size_t)(n0 + r) * DHEAD + d0 + c] = v;
        tile[r][c] = v;
    }
    __syncthreads();
    #pragma unroll
    for (int i = 0; i < 16; i++) {
        int idx = t + i * 256;
        int r = idx >> 6, c = idx & 63;           // r = d index, c = n index
        XbTb[(size_t)(d0 + r) * NSEQ + n0 + c] = tile[c][r];
    }
}

// ---------------- flash attention ----------------
// Per block: QB=64 q rows (4 waves x 16). Swapped QK^T: S^T = mfma(A=K, B=Q),
// C layout col=lane&15 (=q), row=(lane>>4)*4+r (=kcol). PV as out^T = mfma(A=V^T, B=P^T).
__global__ __launch_bounds__(256) void attn_kernel(const u16* __restrict__ Xb,
                                                   const u16* __restrict__ XbT,
                                                   float* __restrict__ out) {
    // K tile [32][128] bf16, XOR-swizzled: byte ^= (row&7)<<4
    __shared__ u16 Klds[KB * DHEAD];
    // V^T tile [128][40] bf16 (32 data cols + 8 pad for bank spread)
    __shared__ u16 Vlds[DHEAD * 40];
    // per-wave P round-trip buffer [16 q][40] (32 data + pad)
    __shared__ u16 Plds[WAVES][16 * 40];

    int bid = blockIdx.x;            // 256 blocks
    int xcd = bid & 7, pos = bid >> 3;
    int b    = xcd >> 1;             // 2 XCDs per batch -> batch data L2-resident
    int qblk = pos + ((xcd & 1) << 5);

    int t = threadIdx.x;
    int w = t >> 6, l = t & 63;
    int lq = l & 15, g = l >> 4;
    int q0 = qblk * QB + w * QW;

    const u16* Xbb  = Xb  + (size_t)b * NSEQ * DHEAD;
    const u16* XbTb = XbT + (size_t)b * DHEAD * NSEQ;

    // Q B-fragments: col=q=lq, k(d) = c*32 + g*8 + i  (contiguous 16B)
    bf16x8 qf[4];
    #pragma unroll
    for (int c = 0; c < 4; c++)
        qf[c] = *(const bf16x8*)(const void*)(Xbb + (size_t)(q0 + lq) * DHEAD + c * 32 + g * 8);

    f32x4 acc[8];                    // out^T d-blocks: col=q=lq, row d = db*16 + g*4 + r
    f32x4 zero = {0.f, 0.f, 0.f, 0.f};
    #pragma unroll
    for (int i = 0; i < 8; i++) acc[i] = zero;
    float m = -1e30f, lsum = 0.f;

    // staging addresses (per thread): K tile 8KB = 256 threads x 2 x 16B
    int o0 = t * 32;
    int krow0 = o0 >> 8, kcol0 = o0 & 255;
    int o1 = o0 + 16;
    int krow1 = o1 >> 8, kcol1 = o1 & 255;
    u16* kdst0 = (u16*)((char*)Klds + (krow0 << 8) + (kcol0 ^ ((krow0 & 7) << 4)));
    u16* kdst1 = (u16*)((char*)Klds + (krow1 << 8) + (kcol1 ^ ((krow1 & 7) << 4)));
    // V^T tile: row d = t>>1 (128 rows), half = t&1 covers 32B = 2x16B
    int vrow = t >> 1, vhalf = t & 1;
    u16* vdst0 = (u16*)((char*)Vlds + vrow * 80 + vhalf * 32);
    u16* vdst1 = vdst0 + 8;

    // prologue: load tile 0 into regs
    bf16x8 kreg0 = *(const bf16x8*)(const void*)(Xbb + (size_t)krow0 * DHEAD + (kcol0 >> 1));
    bf16x8 kreg1 = *(const bf16x8*)(const void*)(Xbb + (size_t)krow1 * DHEAD + (kcol1 >> 1));
    bf16x8 vreg0 = *(const bf16x8*)(const void*)(XbTb + (size_t)vrow * NSEQ + vhalf * 16);
    bf16x8 vreg1 = *(const bf16x8*)(const void*)(XbTb + (size_t)vrow * NSEQ + vhalf * 16 + 8);

    for (int kv0 = 0; kv0 < NSEQ; kv0 += KB) {
        // write staged regs to LDS
        *(bf16x8*)(void*)kdst0 = kreg0;
        *(bf16x8*)(void*)kdst1 = kreg1;
        *(bf16x8*)(void*)vdst0 = vreg0;
        *(bf16x8*)(void*)vdst1 = vreg1;
        __syncthreads();

        // async-stage split: issue next tile's global loads now, they complete during compute
        int nkv = kv0 + KB;
        if (nkv < NSEQ) {
            kreg0 = *(const bf16x8*)(const void*)(Xbb + (size_t)(nkv + krow0) * DHEAD + (kcol0 >> 1));
            kreg1 = *(const bf16x8*)(const void*)(Xbb + (size_t)(nkv + krow1) * DHEAD + (kcol1 >> 1));
            vreg0 = *(const bf16x8*)(const void*)(XbTb + (size_t)vrow * NSEQ + nkv + vhalf * 16);
            vreg1 = *(const bf16x8*)(const void*)(XbTb + (size_t)vrow * NSEQ + nkv + vhalf * 16 + 8);
        }

        // QK^T (swapped): S^T[kcol][q], two 16-kcol halves, K-dim 128 = 4 chunks of 32
        f32x4 s[2];
        s[0] = zero; s[1] = zero;
        #pragma unroll
        for (int half = 0; half < 2; half++) {
            #pragma unroll
            for (int c = 0; c < 4; c++) {
                int row  = half * 16 + lq;
                int colb = c * 64 + g * 16;
                bf16x8 kf = *(const bf16x8*)(const void*)((char*)Klds + (row << 8) + (colb ^ ((row & 7) << 4)));
                s[half] = __builtin_amdgcn_mfma_f32_16x16x32_bf16(kf, qf[c], s[half], 0, 0, 0);
            }
        }

        // online softmax: lane holds 8 kcols (half*16 + g*4 + r) for q = lq
        float tmax = fmaxf(fmaxf(fmaxf(s[0][0], s[0][1]), fmaxf(s[0][2], s[0][3])),
                           fmaxf(fmaxf(s[1][0], s[1][1]), fmaxf(s[1][2], s[1][3])));
        tmax = fmaxf(tmax, __shfl_xor(tmax, 16));
        tmax = fmaxf(tmax, __shfl_xor(tmax, 32));
        float mnew  = fmaxf(m, tmax);
        float scale = __builtin_amdgcn_exp2f((m - mnew) * LOG2E);
        m = mnew;
        float p[8];
        float ps = 0.f;
        #pragma unroll
        for (int i = 0; i < 8; i++) {
            float hv = (i < 4) ? s[0][i & 3] : s[1][i & 3];
            float v = __builtin_amdgcn_exp2f((hv - mnew) * LOG2E);
            p[i] = v;
            ps += v;
        }
        lsum = lsum * scale + ps;
        #pragma unroll
        for (int i = 0; i < 8; i++) acc[i] *= scale;

        // P -> bf16 -> per-wave LDS (P[q][kv]); read back as PV B-fragment
        u32x2 pk0 = { (u32)f2bf(p[0]) | ((u32)f2bf(p[1]) << 16),
                      (u32)f2bf(p[2]) | ((u32)f2bf(p[3]) << 16) };
        u32x2 pk1 = { (u32)f2bf(p[4]) | ((u32)f2bf(p[5]) << 16),
                      (u32)f2bf(p[6]) | ((u32)f2bf(p[7]) << 16) };
        *(u32x2*)(void*)(&Plds[w][lq * 40 + g * 4])      = pk0;
        *(u32x2*)(void*)(&Plds[w][lq * 40 + 16 + g * 4]) = pk1;
        bf16x8 pf = *(const bf16x8*)(const void*)(&Plds[w][lq * 40 + g * 8]);

        // PV: out^T = V^T (16d x 32kv) . P^T (32kv x 16q), 8 d-blocks
        #pragma unroll
        for (int db = 0; db < 8; db++) {
            bf16x8 vf = *(const bf16x8*)(const void*)((char*)Vlds + (db * 16 + lq) * 80 + g * 16);
            acc[db] = __builtin_amdgcn_mfma_f32_16x16x32_bf16(vf, pf, acc[db], 0, 0, 0);
        }
        __syncthreads();   // compute done; next iter may overwrite Klds/Vlds
    }

    // finalize: sum partial lsums across the 4 groups, normalize, store
    lsum += __shfl_xor(lsum, 16);
    lsum += __shfl_xor(lsum, 32);
    float inv = 1.0f / lsum;
    float* op = out + (size_t)b * NSEQ * DHEAD + (size_t)(q0 + lq) * DHEAD;
    #pragma unroll
    for (int db = 0; db < 8; db++) {
        f32x4 r = acc[db];
        r *= inv;
        *(f32x4*)(void*)(op + db * 16 + g * 4) = r;
    }
}

extern "C" void kernel_launch(void* const* d_in, const int* in_sizes, int n_in,
                              void* d_out, int out_size, void* d_ws, size_t ws_size,
                              hipStream_t stream) {
    (void)in_sizes; (void)n_in; (void)out_size; (void)ws_size;
    const float* x = (const float*)d_in[0];
    float* out = (float*)d_out;
    u16* Xb  = (u16*)d_ws;                                  // 4 MB bf16 row-major
    u16* XbT = Xb + (size_t)BATCH * NSEQ * DHEAD;           // 4 MB bf16 transposed
    prep_kernel<<<512, 256, 0, stream>>>(x, Xb, XbT);
    attn_kernel<<<BATCH * (NSEQ / QB), 256, 0, stream>>>(Xb, XbT, out);
}

// Round 2
// 83.886 us; speedup vs baseline: 1.5960x; 1.5960x over previous
//
#include <hip/hip_runtime.h>
#include <stdint.h>

typedef __bf16 bf16;
typedef bf16 bf16x8 __attribute__((ext_vector_type(8)));
typedef float f32x4 __attribute__((ext_vector_type(4)));
typedef uint32_t u32;
typedef uint16_t u16;
typedef u32 u32x2 __attribute__((ext_vector_type(2)));

#define BATCH 4
#define NSEQ  4096
#define DHEAD 128
#define GROUPS 4           // kv-split groups per block
#define QWAVES 4           // q-waves per group (16 q rows each)
#define WAVES  (GROUPS*QWAVES)
#define QB     64          // q rows per block
#define KB     32          // kv rows per tile
#define KVSPAN (NSEQ/GROUPS)
#define LOG2E 1.44269504088896340736f
#define KTILE_B (KB*DHEAD*2)      // 8192 B, XOR-swizzled
#define VROWB   80                // V^T row stride bytes (32 data cols + 8 pad u16)
#define VTILE_B (DHEAD*VROWB)     // 10240 B

__device__ __forceinline__ u16 f2bf(float f) {
    u32 u = __builtin_bit_cast(u32, f);
    u += 0x7fff + ((u >> 16) & 1);   // RNE; inputs are finite normals
    return (u16)(u >> 16);
}

// ---------------- prep: fp32 x -> bf16 Xb (row-major) + XbT (transposed) ----------------
__global__ __launch_bounds__(256) void prep_kernel(const float* __restrict__ x,
                                                   u16* __restrict__ Xb,
                                                   u16* __restrict__ XbT) {
    __shared__ u16 tile[64][65];
    int bid = blockIdx.x;            // 512 blocks: b(4) x ntile(64) x dtile(2)
    int b  = bid >> 7;
    int nt = (bid >> 1) & 63;
    int dt = bid & 1;
    int n0 = nt * 64, d0 = dt * 64;
    int t = threadIdx.x;
    const float* xb = x + (size_t)b * NSEQ * DHEAD;
    u16* Xbb  = Xb  + (size_t)b * NSEQ * DHEAD;
    u16* XbTb = XbT + (size_t)b * DHEAD * NSEQ;
    #pragma unroll
    for (int i = 0; i < 16; i++) {
        int idx = t + i * 256;
        int r = idx >> 6, c = idx & 63;
        float f = xb[(size_t)(n0 + r) * DHEAD + d0 + c];
        u16 v = f2bf(f);
        Xbb[(size_t)(n0 + r) * DHEAD + d0 + c] = v;
        tile[r][c] = v;
    }
    __syncthreads();
    #pragma unroll
    for (int i = 0; i < 16; i++) {
        int idx = t + i * 256;
        int r = idx >> 6, c = idx & 63;           // r = d index, c = n index
        XbTb[(size_t)(d0 + r) * NSEQ + n0 + c] = tile[c][r];
    }
}

// ---------------- flash attention, 4-way KV split ----------------
// 16 waves: grp = w>>2 sweeps kv [grp*1024, +1024); wq = w&3 owns 16 q rows.
// Swapped QK^T: S^T = mfma(A=K, B=Q), C col=lane&15 (=q), row=(lane>>4)*4+r (=kcol).
// PV as out^T = mfma(A=V^T, B=P^T). Partials combined through LDS at the end.
__global__ __launch_bounds__(1024, 4) void attn_kernel(const u16* __restrict__ Xb,
                                                       const u16* __restrict__ XbT,
                                                       float* __restrict__ out) {
    __shared__ char smem[GROUPS * (KTILE_B + VTILE_B)];   // 73728 B; Obuf (32KB) in epilogue
    __shared__ u16 Plds[WAVES][16 * 40];                  // per-wave P round-trip
    __shared__ float Mx[GROUPS][QWAVES][16];
    __shared__ float Lx[GROUPS][QWAVES][16];

    int bid = blockIdx.x;            // 256 blocks, 1 per CU
    int xcd = bid & 7, pos = bid >> 3;
    int b    = xcd >> 1;             // 2 XCDs per batch -> batch data L2-resident
    int qblk = pos + ((xcd & 1) << 5);

    int t = threadIdx.x;
    int w = t >> 6, l = t & 63;
    int grp = w >> 2, wq = w & 3;
    int lq = l & 15, g = l >> 4;
    int q0 = qblk * QB + wq * 16;
    int tg = t & 255;                // thread id within group (4 waves)

    char* Kg = smem + grp * KTILE_B;
    char* Vg = smem + GROUPS * KTILE_B + grp * VTILE_B;

    const u16* Xbb  = Xb  + (size_t)b * NSEQ * DHEAD;
    const u16* XbTb = XbT + (size_t)b * DHEAD * NSEQ;

    // Q B-fragments: col=q=lq, k(d) = c*32 + g*8 + i
    bf16x8 qf[4];
    #pragma unroll
    for (int c = 0; c < 4; c++)
        qf[c] = *(const bf16x8*)(const void*)(Xbb + (size_t)(q0 + lq) * DHEAD + c * 32 + g * 8);

    f32x4 acc[8];                    // out^T d-blocks: col=q=lq, row d = db*16 + g*4 + r
    f32x4 zero = {0.f, 0.f, 0.f, 0.f};
    #pragma unroll
    for (int i = 0; i < 8; i++) acc[i] = zero;
    float m = -1e30f, lsum = 0.f;

    // staging addresses: K tile 8KB = 256 threads x 2 x 16B, XOR-swizzled rows
    int o0 = tg * 32;
    int krow0 = o0 >> 8, kcol0 = o0 & 255;
    int o1 = o0 + 16;
    int krow1 = o1 >> 8, kcol1 = o1 & 255;
    u16* kdst0 = (u16*)(Kg + (krow0 << 8) + (kcol0 ^ ((krow0 & 7) << 4)));
    u16* kdst1 = (u16*)(Kg + (krow1 << 8) + (kcol1 ^ ((krow1 & 7) << 4)));
    // V^T tile: row d = tg>>1 (128 rows), half = tg&1 covers 32B
    int vrow = tg >> 1, vhalf = tg & 1;
    u16* vdst0 = (u16*)(Vg + vrow * VROWB + vhalf * 32);
    u16* vdst1 = vdst0 + 8;
    const u16* vsrcrow = XbTb + (size_t)vrow * NSEQ + vhalf * 16;

    int kvbase = grp * KVSPAN;
    int kvend  = kvbase + KVSPAN;

    // prologue: load this group's tile 0 into regs
    bf16x8 kreg0 = *(const bf16x8*)(const void*)(Xbb + (size_t)(kvbase + krow0) * DHEAD + (kcol0 >> 1));
    bf16x8 kreg1 = *(const bf16x8*)(const void*)(Xbb + (size_t)(kvbase + krow1) * DHEAD + (kcol1 >> 1));
    bf16x8 vreg0 = *(const bf16x8*)(const void*)(vsrcrow + kvbase);
    bf16x8 vreg1 = *(const bf16x8*)(const void*)(vsrcrow + kvbase + 8);

    for (int kv0 = kvbase; kv0 < kvend; kv0 += KB) {
        // write staged regs to LDS
        *(bf16x8*)(void*)kdst0 = kreg0;
        *(bf16x8*)(void*)kdst1 = kreg1;
        *(bf16x8*)(void*)vdst0 = vreg0;
        *(bf16x8*)(void*)vdst1 = vreg1;
        __syncthreads();

        // async-stage split: issue next tile's global loads; complete during compute
        int nkv = kv0 + KB;
        if (nkv < kvend) {
            kreg0 = *(const bf16x8*)(const void*)(Xbb + (size_t)(nkv + krow0) * DHEAD + (kcol0 >> 1));
            kreg1 = *(const bf16x8*)(const void*)(Xbb + (size_t)(nkv + krow1) * DHEAD + (kcol1 >> 1));
            vreg0 = *(const bf16x8*)(const void*)(vsrcrow + nkv);
            vreg1 = *(const bf16x8*)(const void*)(vsrcrow + nkv + 8);
        }

        // QK^T (swapped): S^T[kcol][q], two 16-kcol halves, d = 4 chunks of 32
        f32x4 s[2];
        s[0] = zero; s[1] = zero;
        #pragma unroll
        for (int half = 0; half < 2; half++) {
            #pragma unroll
            for (int c = 0; c < 4; c++) {
                int row  = half * 16 + lq;
                int colb = c * 64 + g * 16;
                bf16x8 kf = *(const bf16x8*)(const void*)(Kg + (row << 8) + (colb ^ ((row & 7) << 4)));
                s[half] = __builtin_amdgcn_mfma_f32_16x16x32_bf16(kf, qf[c], s[half], 0, 0, 0);
            }
        }

        // online softmax: lane holds 8 kcols (half*16 + g*4 + r) for q = lq
        float tmax = fmaxf(fmaxf(fmaxf(s[0][0], s[0][1]), fmaxf(s[0][2], s[0][3])),
                           fmaxf(fmaxf(s[1][0], s[1][1]), fmaxf(s[1][2], s[1][3])));
        tmax = fmaxf(tmax, __shfl_xor(tmax, 16));
        tmax = fmaxf(tmax, __shfl_xor(tmax, 32));
        // defer-max fast path (threshold 0: numerically exact skip)
        if (!__all(tmax <= m)) {
            float mnew  = fmaxf(m, tmax);
            float scale = __builtin_amdgcn_exp2f((m - mnew) * LOG2E);
            lsum *= scale;
            #pragma unroll
            for (int i = 0; i < 8; i++) acc[i] *= scale;
            m = mnew;
        }
        float p[8];
        float ps = 0.f;
        #pragma unroll
        for (int i = 0; i < 8; i++) {
            float hv = (i < 4) ? s[0][i & 3] : s[1][i & 3];
            float v = __builtin_amdgcn_exp2f((hv - m) * LOG2E);
            p[i] = v;
            ps += v;
        }
        lsum += ps;

        // P -> bf16 -> per-wave LDS (P[q][kv]); read back as PV B-fragment
        u32x2 pk0 = { (u32)f2bf(p[0]) | ((u32)f2bf(p[1]) << 16),
                      (u32)f2bf(p[2]) | ((u32)f2bf(p[3]) << 16) };
        u32x2 pk1 = { (u32)f2bf(p[4]) | ((u32)f2bf(p[5]) << 16),
                      (u32)f2bf(p[6]) | ((u32)f2bf(p[7]) << 16) };
        *(u32x2*)(void*)(&Plds[w][lq * 40 + g * 4])      = pk0;
        *(u32x2*)(void*)(&Plds[w][lq * 40 + 16 + g * 4]) = pk1;
        bf16x8 pf = *(const bf16x8*)(const void*)(&Plds[w][lq * 40 + g * 8]);

        // PV: out^T = V^T (16d x 32kv) . P^T (32kv x 16q), 8 d-blocks
        #pragma unroll
        for (int db = 0; db < 8; db++) {
            bf16x8 vf = *(const bf16x8*)(const void*)(Vg + (db * 16 + lq) * VROWB + g * 16);
            acc[db] = __builtin_amdgcn_mfma_f32_16x16x32_bf16(vf, pf, acc[db], 0, 0, 0);
        }
        __syncthreads();   // compute done; next iter overwrites Kg/Vg
    }

    // ---- combine the 4 kv-groups' partials ----
    lsum += __shfl_xor(lsum, 16);
    lsum += __shfl_xor(lsum, 32);
    if (g == 0) { Mx[grp][wq][lq] = m; Lx[grp][wq][lq] = lsum; }
    __syncthreads();

    float mtot = Mx[0][wq][lq];
    #pragma unroll
    for (int j = 1; j < GROUPS; j++) mtot = fmaxf(mtot, Mx[j][wq][lq]);
    float ltot = 0.f;
    #pragma unroll
    for (int j = 0; j < GROUPS; j++)
        ltot += Lx[j][wq][lq] * __builtin_amdgcn_exp2f((Mx[j][wq][lq] - mtot) * LOG2E);
    float coef = __builtin_amdgcn_exp2f((m - mtot) * LOG2E);

    float* orow = (float*)smem + (size_t)(wq * 16 + lq) * DHEAD;   // Obuf aliases staging LDS
    if (grp == 0) {
        #pragma unroll
        for (int db = 0; db < 8; db++) {
            f32x4 r = acc[db]; r *= coef;
            *(f32x4*)(void*)(orow + db * 16 + g * 4) = r;
        }
    }
    __syncthreads();
    if (grp == 1) {
        #pragma unroll
        for (int db = 0; db < 8; db++) {
            f32x4 r = *(const f32x4*)(const void*)(orow + db * 16 + g * 4);
            r += acc[db] * coef;
            *(f32x4*)(void*)(orow + db * 16 + g * 4) = r;
        }
    }
    __syncthreads();
    if (grp == 2) {
        #pragma unroll
        for (int db = 0; db < 8; db++) {
            f32x4 r = *(const f32x4*)(const void*)(orow + db * 16 + g * 4);
            r += acc[db] * coef;
            *(f32x4*)(void*)(orow + db * 16 + g * 4) = r;
        }
    }
    __syncthreads();
    if (grp == 3) {
        float inv = 1.0f / ltot;
        float* op = out + (size_t)b * NSEQ * DHEAD + (size_t)(q0 + lq) * DHEAD;
        #pragma unroll
        for (int db = 0; db < 8; db++) {
            f32x4 r = *(const f32x4*)(const void*)(orow + db * 16 + g * 4);
            r += acc[db] * coef;
            r *= inv;
            *(f32x4*)(void*)(op + db * 16 + g * 4) = r;
        }
    }
}

extern "C" void kernel_launch(void* const* d_in, const int* in_sizes, int n_in,
                              void* d_out, int out_size, void* d_ws, size_t ws_size,
                              hipStream_t stream) {
    (void)in_sizes; (void)n_in; (void)out_size; (void)ws_size;
    const float* x = (const float*)d_in[0];
    float* out = (float*)d_out;
    u16* Xb  = (u16*)d_ws;                                  // 4 MB bf16 row-major
    u16* XbT = Xb + (size_t)BATCH * NSEQ * DHEAD;           // 4 MB bf16 transposed
    prep_kernel<<<512, 256, 0, stream>>>(x, Xb, XbT);
    attn_kernel<<<BATCH * (NSEQ / QB), 1024, 0, stream>>>(Xb, XbT, out);
}

// Round 4
// 67.320 us; speedup vs baseline: 1.9888x; 1.2461x over previous
//
#include <hip/hip_runtime.h>
#include <stdint.h>

typedef __bf16 bf16;
typedef bf16 bf16x2 __attribute__((ext_vector_type(2)));
typedef bf16 bf16x8 __attribute__((ext_vector_type(8)));
typedef float f32x4 __attribute__((ext_vector_type(4)));
typedef float f32x16 __attribute__((ext_vector_type(16)));
typedef uint32_t u32;
typedef uint16_t u16;
typedef u32 u32x4 __attribute__((ext_vector_type(4)));

#define BATCH 4
#define NSEQ  4096
#define DHEAD 128
#define GROUPS 4
#define KB    32
#define KVSPAN (NSEQ/GROUPS)      // 1024
#define NITER  (KVSPAN/KB)        // 32
#define LOG2E 1.44269504088896340736f
#define KTILE 8192                // K tile [32][256B], byte ^= (row&7)<<4
#define VTILE 8192                // V^T tile [128][64B], byte ^= ((row>>1)&3)<<4
#define GBUF  (KTILE+VTILE)       // 16 KB per group per buffer
#define BUFSZ (GROUPS*GBUF)       // 64 KB per buffer
#define OROW  136                 // epilogue Obuf row stride (floats)

__device__ __forceinline__ u16 f2bf(float f) {
    u32 u = __builtin_bit_cast(u32, f);
    u += 0x7fff + ((u >> 16) & 1);   // RNE
    return (u16)(u >> 16);
}

// ---------------- prep: fp32 x -> bf16 Xb (row-major) + XbT (transposed) ----------------
__global__ __launch_bounds__(256) void prep_kernel(const float* __restrict__ x,
                                                   u16* __restrict__ Xb,
                                                   u16* __restrict__ XbT) {
    __shared__ u16 tile[64][65];
    int bid = blockIdx.x;
    int b  = bid >> 7;
    int nt = (bid >> 1) & 63;
    int dt = bid & 1;
    int n0 = nt * 64, d0 = dt * 64;
    int t = threadIdx.x;
    const float* xb = x + (size_t)b * NSEQ * DHEAD;
    u16* Xbb  = Xb  + (size_t)b * NSEQ * DHEAD;
    u16* XbTb = XbT + (size_t)b * DHEAD * NSEQ;
    #pragma unroll
    for (int i = 0; i < 16; i++) {
        int idx = t + i * 256;
        int r = idx >> 6, c = idx & 63;
        float f = xb[(size_t)(n0 + r) * DHEAD + d0 + c];
        u16 v = f2bf(f);
        Xbb[(size_t)(n0 + r) * DHEAD + d0 + c] = v;
        tile[r][c] = v;
    }
    __syncthreads();
    #pragma unroll
    for (int i = 0; i < 16; i++) {
        int idx = t + i * 256;
        int r = idx >> 6, c = idx & 63;
        XbTb[(size_t)(d0 + r) * NSEQ + n0 + c] = tile[c][r];
    }
}

// ---------------- flash attention: 32x32 MFMA, in-register P, dbuf LDS ----------------
// 8 waves = 4 kv-groups x 2 q-waves (32 q rows each). Swapped QK^T: S^T = mfma(A=Ktile, B=Q^T):
// C col=lane&31 (=q), row=(reg&3)+8*(reg>>2)+4*(lane>>5) (=kv). PV: out^T = mfma(A=V^T, B=P^T)
// with P^T built in-register via bf16 pack + permlane32_swap (distinct-arg form only).
__global__ __launch_bounds__(512, 2) void attn_kernel(const u16* __restrict__ Xb,
                                                      const u16* __restrict__ XbT,
                                                      float* __restrict__ out) {
    __shared__ __align__(16) char smem[2 * BUFSZ];      // 128 KB staging; Obuf aliases in epilogue
    __shared__ float Mx[GROUPS][64];
    __shared__ float Lx[GROUPS][64];

    int bid = blockIdx.x;            // 256 blocks, 1/CU
    int xcd = bid & 7, pos = bid >> 3;
    int b    = xcd >> 1;             // 2 XCDs per batch -> batch L2-resident
    int qblk = pos + ((xcd & 1) << 5);

    int t = threadIdx.x;
    int w = t >> 6, l = t & 63;
    int grp = w >> 1, wq = w & 1;
    int tg = t & 127;                // thread within group (2 waves)
    int r  = l & 31;                 // lane row (m/n index)
    int hh = l >> 5;                 // k-half
    int hhx = hh << 4;
    int qn = wq * 32 + r;            // q row within block (0..63)
    int q0 = qblk * 64 + qn;

    const u16* Xbb  = Xb  + (size_t)b * NSEQ * DHEAD;
    const u16* XbTb = XbT + (size_t)b * DHEAD * NSEQ;

    // fragment-read lane constants (conflict-free swizzled)
    int kfull = (r << 8) + (hhx ^ ((r & 7) << 4));          // + XOR (dc<<5)
    int vfull = (r << 6) + (hhx ^ (((r >> 1) & 3) << 4));   // + db*2048, XOR (ks<<5)

    // Q B-fragments: n=q=r, k(d) = dc*16 + hh*8 + i
    bf16x8 qf[8];
    const u16* qrow = Xbb + (size_t)q0 * DHEAD;
    #pragma unroll
    for (int dc = 0; dc < 8; dc++)
        qf[dc] = *(const bf16x8*)(const void*)(qrow + dc * 16 + hh * 8);

    f32x16 zz = {0.f,0.f,0.f,0.f,0.f,0.f,0.f,0.f,0.f,0.f,0.f,0.f,0.f,0.f,0.f,0.f};
    f32x16 acc[4];                   // out^T d-blocks: d = db*32 + (reg&3)+8*(reg>>2)+4*hh, q=r
    acc[0] = zz; acc[1] = zz; acc[2] = zz; acc[3] = zz;
    float m = -1e30f, lsum = 0.f;

    int kvbase = grp * KVSPAN;
    bf16x8 kreg[4], vreg[4];

    // prologue: stage tile 0
    #pragma unroll
    for (int j = 0; j < 4; j++) {
        int L = (j * 128 + tg) * 16;
        int row = L >> 8, csw = L & 255;
        int scol = csw ^ ((row & 7) << 4);
        kreg[j] = *(const bf16x8*)(const void*)(Xbb + ((size_t)(kvbase + row) << 7) + (scol >> 1));
        int vrow = L >> 6, vcsw = L & 63;
        int vscol = vcsw ^ (((vrow >> 1) & 3) << 4);
        vreg[j] = *(const bf16x8*)(const void*)(XbTb + (size_t)vrow * NSEQ + kvbase + (vscol >> 1));
    }
    {
        char* nK = smem + grp * GBUF;
        char* nV = nK + KTILE;
        #pragma unroll
        for (int j = 0; j < 4; j++) {
            *(bf16x8*)(void*)(nK + (j * 128 + tg) * 16) = kreg[j];
            *(bf16x8*)(void*)(nV + (j * 128 + tg) * 16) = vreg[j];
        }
    }
    __syncthreads();

    for (int it = 0; it < NITER; it++) {
        const char* cK = smem + (it & 1) * BUFSZ + grp * GBUF;
        const char* cV = cK + KTILE;
        bool more = (it + 1 < NITER);
        int nkv = kvbase + (it + 1) * KB;

        // issue next tile's global loads (complete during compute)
        if (more) {
            #pragma unroll
            for (int j = 0; j < 4; j++) {
                int L = (j * 128 + tg) * 16;
                int row = L >> 8, csw = L & 255;
                int scol = csw ^ ((row & 7) << 4);
                kreg[j] = *(const bf16x8*)(const void*)(Xbb + ((size_t)(nkv + row) << 7) + (scol >> 1));
                int vrow = L >> 6, vcsw = L & 63;
                int vscol = vcsw ^ (((vrow >> 1) & 3) << 4);
                vreg[j] = *(const bf16x8*)(const void*)(XbTb + (size_t)vrow * NSEQ + nkv + (vscol >> 1));
            }
        }

        // QK^T: S^T[kv][q], 8 d-chunks, 2 accumulator chains
        f32x16 sa = zz, sb = zz;
        #pragma unroll
        for (int dc = 0; dc < 8; dc += 2) {
            bf16x8 kf0 = *(const bf16x8*)(const void*)(cK + (kfull ^ (dc << 5)));
            sa = __builtin_amdgcn_mfma_f32_32x32x16_bf16(kf0, qf[dc], sa, 0, 0, 0);
            bf16x8 kf1 = *(const bf16x8*)(const void*)(cK + (kfull ^ ((dc + 1) << 5)));
            sb = __builtin_amdgcn_mfma_f32_32x32x16_bf16(kf1, qf[dc + 1], sb, 0, 0, 0);
        }
        f32x16 s = sa + sb;

        // online softmax: lane holds 16 kv rows for q=r
        float tmax = s[0];
        #pragma unroll
        for (int i = 1; i < 16; i++) tmax = fmaxf(tmax, s[i]);
        tmax = fmaxf(tmax, __shfl_xor(tmax, 32));   // cross-half (lanes l <-> l+32, same q)
        if (!__all(tmax <= m)) {     // exact defer-max: skip rescale when no new max
            float mnew = fmaxf(m, tmax);
            float sc = __builtin_amdgcn_exp2f((m - mnew) * LOG2E);
            lsum *= sc;
            #pragma unroll
            for (int db = 0; db < 4; db++) acc[db] *= sc;
            m = mnew;
        }
        float mL = m * LOG2E;
        float p[16];
        float ps = 0.f;
        #pragma unroll
        for (int i = 0; i < 16; i++) {
            float pv = __builtin_amdgcn_exp2f(s[i] * LOG2E - mL);
            p[i] = pv; ps += pv;
        }
        lsum += ps;

        // P -> bf16 pairs -> permlane32_swap -> PV B-fragments (no LDS)
        u32 c01   = __builtin_bit_cast(u32, (bf16x2){(bf16)p[0],  (bf16)p[1]});
        u32 c23   = __builtin_bit_cast(u32, (bf16x2){(bf16)p[2],  (bf16)p[3]});
        u32 c89   = __builtin_bit_cast(u32, (bf16x2){(bf16)p[4],  (bf16)p[5]});
        u32 c1011 = __builtin_bit_cast(u32, (bf16x2){(bf16)p[6],  (bf16)p[7]});
        u32 cA    = __builtin_bit_cast(u32, (bf16x2){(bf16)p[8],  (bf16)p[9]});
        u32 cB    = __builtin_bit_cast(u32, (bf16x2){(bf16)p[10], (bf16)p[11]});
        u32 cC    = __builtin_bit_cast(u32, (bf16x2){(bf16)p[12], (bf16)p[13]});
        u32 cD    = __builtin_bit_cast(u32, (bf16x2){(bf16)p[14], (bf16)p[15]});
        auto sA = __builtin_amdgcn_permlane32_swap(c01, c89,   false, false);
        auto sB = __builtin_amdgcn_permlane32_swap(c23, c1011, false, false);
        auto sC = __builtin_amdgcn_permlane32_swap(cA, cC,     false, false);
        auto sD = __builtin_amdgcn_permlane32_swap(cB, cD,     false, false);
        bf16x8 pb0 = __builtin_bit_cast(bf16x8, (u32x4){sA[0], sB[0], sA[1], sB[1]});
        bf16x8 pb1 = __builtin_bit_cast(bf16x8, (u32x4){sC[0], sD[0], sC[1], sD[1]});

        // PV: out^T += V^T . P^T, 4 d-blocks x 2 k-steps
        #pragma unroll
        for (int db = 0; db < 4; db++) {
            const char* vb = cV + (db << 11);
            bf16x8 vf0 = *(const bf16x8*)(const void*)(vb + (vfull ^ 0));
            acc[db] = __builtin_amdgcn_mfma_f32_32x32x16_bf16(vf0, pb0, acc[db], 0, 0, 0);
            bf16x8 vf1 = *(const bf16x8*)(const void*)(vb + (vfull ^ 32));
            acc[db] = __builtin_amdgcn_mfma_f32_32x32x16_bf16(vf1, pb1, acc[db], 0, 0, 0);
        }

        // write staged regs into the other buffer
        if (more) {
            char* nK = smem + ((it + 1) & 1) * BUFSZ + grp * GBUF;
            char* nV = nK + KTILE;
            #pragma unroll
            for (int j = 0; j < 4; j++) {
                *(bf16x8*)(void*)(nK + (j * 128 + tg) * 16) = kreg[j];
                *(bf16x8*)(void*)(nV + (j * 128 + tg) * 16) = vreg[j];
            }
        }
        __syncthreads();
    }

    // ---- combine 4 kv-groups ----
    lsum += __shfl_xor(lsum, 32);    // cross-half total
    if (l < 32) { Mx[grp][qn] = m; Lx[grp][qn] = lsum; }
    __syncthreads();

    float mtot = fmaxf(fmaxf(Mx[0][qn], Mx[1][qn]), fmaxf(Mx[2][qn], Mx[3][qn]));
    float coef = __builtin_amdgcn_exp2f((m - mtot) * LOG2E);

    float* Obuf = (float*)smem;      // [64][OROW] aliases staging (safe after final barrier)
    #pragma unroll
    for (int j = 0; j < GROUPS; j++) {
        if (grp == j) {
            #pragma unroll
            for (int db = 0; db < 4; db++) {
                #pragma unroll
                for (int rq = 0; rq < 4; rq++) {
                    int d0 = db * 32 + rq * 8 + hh * 4;
                    float* dst = Obuf + qn * OROW + d0;
                    f32x4 v = { acc[db][rq*4+0], acc[db][rq*4+1], acc[db][rq*4+2], acc[db][rq*4+3] };
                    v *= coef;
                    if (j > 0) v += *(const f32x4*)(const void*)dst;
                    *(f32x4*)(void*)dst = v;
                }
            }
        }
        __syncthreads();
    }

    // coalesced final store: thread t -> row q2 = t>>3, 16 floats at (t&7)*16
    int q2 = t >> 3;
    float mt = fmaxf(fmaxf(Mx[0][q2], Mx[1][q2]), fmaxf(Mx[2][q2], Mx[3][q2]));
    float lt = 0.f;
    #pragma unroll
    for (int j = 0; j < GROUPS; j++)
        lt += Lx[j][q2] * __builtin_amdgcn_exp2f((Mx[j][q2] - mt) * LOG2E);
    float inv = 1.0f / lt;
    const float* srow = Obuf + q2 * OROW + (t & 7) * 16;
    float* orow = out + ((size_t)b * NSEQ + qblk * 64 + q2) * DHEAD + (t & 7) * 16;
    #pragma unroll
    for (int k = 0; k < 4; k++) {
        f32x4 v = *(const f32x4*)(const void*)(srow + k * 4);
        v *= inv;
        *(f32x4*)(void*)(orow + k * 4) = v;
    }
}

extern "C" void kernel_launch(void* const* d_in, const int* in_sizes, int n_in,
                              void* d_out, int out_size, void* d_ws, size_t ws_size,
                              hipStream_t stream) {
    (void)in_sizes; (void)n_in; (void)out_size; (void)ws_size;
    const float* x = (const float*)d_in[0];
    float* out = (float*)d_out;
    u16* Xb  = (u16*)d_ws;
    u16* XbT = Xb + (size_t)BATCH * NSEQ * DHEAD;
    prep_kernel<<<512, 256, 0, stream>>>(x, Xb, XbT);
    attn_kernel<<<BATCH * (NSEQ / 64), 512, 0, stream>>>(Xb, XbT, out);
}